// Round 7
// baseline (334.298 us; speedup 1.0000x reference)
//
#include <hip/hip_runtime.h>
#include <stdint.h>

#define B_ 4
#define N_ 2048
#define M_ 2048
#define C_ 1024
#define H_ 16
#define D_ 64
#define SC_ (B_*N_*C_)
#define CC_ (C_*C_)

typedef unsigned short u16;
typedef __attribute__((ext_vector_type(8))) short short8;
typedef __attribute__((ext_vector_type(4))) short short4v;
typedef __attribute__((ext_vector_type(4))) float f32x4;

#if __has_builtin(__builtin_amdgcn_exp2f)
#define EXP2F __builtin_amdgcn_exp2f
#else
#define EXP2F exp2f
#endif

__device__ inline u16 f2bf(float f) {
    union { float f; uint32_t u; } v; v.f = f;
    uint32_t r = v.u + 0x7fffu + ((v.u >> 16) & 1u);
    return (u16)(r >> 16);
}

// K=16 bf16 MFMA (v_mfma_f32_16x16x16_bf16): 2-reg operands, no zero padding.
__device__ inline f32x4 mfma16x16x16_bf16(short4v a, short4v b, f32x4 c) {
#if __has_builtin(__builtin_amdgcn_mfma_f32_16x16x16bf16_1k)
    return __builtin_amdgcn_mfma_f32_16x16x16bf16_1k(a, b, c, 0, 0, 0);
#else
    asm volatile("v_mfma_f32_16x16x16_bf16 %0, %1, %2, %0"
                 : "+v"(c) : "v"(a), "v"(b));
    return c;
#endif
}

__device__ inline void gll16(const u16* g, u16* l) {
    __builtin_amdgcn_global_load_lds(
        (const __attribute__((address_space(1))) void*)g,
        (__attribute__((address_space(3))) void*)l, 16, 0, 0);
}

// Counted-vmcnt barrier: retire all but the newest N VMEM ops, then block
// barrier. sched_barrier(0) keeps LDS reads from hoisting above (rule #18).
#define WAIT_BARRIER(N)                                         \
    do {                                                        \
        asm volatile("s_waitcnt vmcnt(" #N ")" ::: "memory");   \
        __builtin_amdgcn_s_barrier();                           \
        __builtin_amdgcn_sched_barrier(0);                      \
    } while (0)

// ---------------- pass 1: fp32 -> bf16 conversion of all GEMM inputs ----------
__global__ __launch_bounds__(256) void convert_kernel(
    const float* __restrict__ q, const float* __restrict__ k, const float* __restrict__ v,
    const float* __restrict__ wq, const float* __restrict__ wk,
    const float* __restrict__ wv, const float* __restrict__ wp,
    u16* __restrict__ qf, u16* __restrict__ kf, u16* __restrict__ vf,
    u16* __restrict__ wqb, u16* __restrict__ wkb, u16* __restrict__ wvb, u16* __restrict__ wpb)
{
    const int SC4 = SC_ / 4;
    const int CC4 = CC_ / 4;
    const int total = 3 * SC4 + 4 * CC4;
    for (int i = blockIdx.x * 256 + threadIdx.x; i < total; i += gridDim.x * 256) {
        const float* src; u16* dst; int off;
        if (i < 3 * SC4) {
            int seg = i >> 21;
            off = (i & (SC4 - 1)) << 2;
            src = seg == 0 ? q : seg == 1 ? k : v;
            dst = seg == 0 ? qf : seg == 1 ? kf : vf;
        } else {
            int j = i - 3 * SC4;
            int seg = j >> 18;
            off = (j & (CC4 - 1)) << 2;
            src = seg == 0 ? wq : seg == 1 ? wk : seg == 2 ? wv : wp;
            dst = seg == 0 ? wqb : seg == 1 ? wkb : seg == 2 ? wvb : wpb;
        }
        float4 val = *(const float4*)(src + off);
        ushort4 h;
        h.x = f2bf(val.x); h.y = f2bf(val.y); h.z = f2bf(val.z); h.w = f2bf(val.w);
        *(ushort4*)(dst + off) = h;
    }
}

// ---------------- merged Q/K/V projection GEMM, 1536 blocks -------------------
__global__ __launch_bounds__(256, 3) void gemm_qkv(
    const u16* __restrict__ A0, const u16* __restrict__ W0, u16* __restrict__ O0,
    const u16* __restrict__ A1, const u16* __restrict__ W1, u16* __restrict__ O1,
    const u16* __restrict__ A2, const u16* __restrict__ W2, u16* __restrict__ O2,
    float qscale)
{
    const int K = 1024;
    __shared__ u16 SH[3 * 8192];   // [buf 3][As 4096 u16 | Bs 4096 u16] = 48 KB
    const int tid = threadIdx.x;
    const int wid = tid >> 6, lane = tid & 63;
    const int quad = lane >> 4, l15 = lane & 15;
    const int gseg = blockIdx.x >> 9;
    const int f = blockIdx.x & 511;
    const u16* A  = gseg == 0 ? A0 : gseg == 1 ? A1 : A2;
    const u16* Wb = gseg == 0 ? W0 : gseg == 1 ? W1 : W2;
    u16* Op       = gseg == 0 ? O0 : gseg == 1 ? O1 : O2;
    const float scale = gseg == 2 ? qscale : 1.0f;

    const int m0 = (f & 63) * 128, n0 = (f >> 6) * 128;
    const int wm = (wid >> 1) * 64, wn = (wid & 1) * 64;

    size_t aoff[2], boff[2];
    int dsto[2];
#pragma unroll
    for (int i = 0; i < 2; ++i) {
        int s = tid + i * 256;
        int row = s >> 2, c8 = (s & 3) << 3;
        aoff[i] = (size_t)(m0 + row) * K + c8;
        boff[i] = (size_t)(n0 + row) * K + c8;
        dsto[i] = s * 8;
    }

    f32x4 acc[4][4];
#pragma unroll
    for (int i = 0; i < 4; ++i)
#pragma unroll
        for (int j = 0; j < 4; ++j) acc[i][j] = f32x4{0.f, 0.f, 0.f, 0.f};

#pragma unroll
    for (int t = 0; t < 2; ++t) {
        const int bo = t * 8192, k0 = t * 32;
#pragma unroll
        for (int i = 0; i < 2; ++i) {
            gll16(A + aoff[i] + k0, SH + bo + dsto[i]);
            gll16(Wb + boff[i] + k0, SH + bo + 4096 + dsto[i]);
        }
    }

    for (int it = 0; it < 32; ++it) {
        const int cur = (it % 3) * 8192;
        if (it < 31) WAIT_BARRIER(4);
        else         WAIT_BARRIER(0);
        if (it + 2 < 32) {
            const int nxt = ((it + 2) % 3) * 8192;
            const int k0n = (it + 2) * 32;
#pragma unroll
            for (int i = 0; i < 2; ++i) {
                gll16(A + aoff[i] + k0n, SH + nxt + dsto[i]);
                gll16(Wb + boff[i] + k0n, SH + nxt + 4096 + dsto[i]);
            }
        }
        short8 av[4], bv[4];
#pragma unroll
        for (int i = 0; i < 4; ++i)
            av[i] = *(const short8*)(SH + cur + (wm + i * 16 + l15) * 32 + quad * 8);
#pragma unroll
        for (int j = 0; j < 4; ++j)
            bv[j] = *(const short8*)(SH + cur + 4096 + (wn + j * 16 + l15) * 32 + quad * 8);
#pragma unroll
        for (int i = 0; i < 4; ++i)
#pragma unroll
            for (int j = 0; j < 4; ++j)
                acc[i][j] = __builtin_amdgcn_mfma_f32_16x16x32_bf16(av[i], bv[j], acc[i][j], 0, 0, 0);
    }

    if (gseg == 1) {   // V-proj: vT[((b*16+h)*64+d)][m]
#pragma unroll
        for (int j = 0; j < 4; ++j) {
            int col = n0 + wn + j * 16 + l15;
            int hh = col >> 6, dd = col & 63;
#pragma unroll
            for (int i = 0; i < 4; ++i) {
                int row = m0 + wm + i * 16 + quad * 4;
                int bb = row >> 11, mm = row & 2047;
                ushort4 hv;
                hv.x = f2bf(acc[i][j][0]);
                hv.y = f2bf(acc[i][j][1]);
                hv.z = f2bf(acc[i][j][2]);
                hv.w = f2bf(acc[i][j][3]);
                *(ushort4*)(Op + (((size_t)bb * 16 + hh) * 64 + dd) * 2048 + mm) = hv;
            }
        }
    } else {           // K-proj / Q-proj: row-major bf16 (Q pre-scaled)
#pragma unroll
        for (int j = 0; j < 4; ++j) {
            int col = n0 + wn + j * 16 + l15;
#pragma unroll
            for (int i = 0; i < 4; ++i) {
                int row = m0 + wm + i * 16 + quad * 4;
#pragma unroll
                for (int r = 0; r < 4; ++r)
                    Op[(size_t)(row + r) * 1024 + col] = f2bf(acc[i][j][r] * scale);
            }
        }
    }
}

// ---------------- final projection GEMM (fp32 out + bias) ---------------------
__global__ __launch_bounds__(256) void gemm_p(
    const u16* __restrict__ A, const u16* __restrict__ Wb,
    const float* __restrict__ bias, float* __restrict__ Op)
{
    const int K = 1024;
    __shared__ u16 SH[3 * 8192];
    const int tid = threadIdx.x;
    const int wid = tid >> 6, lane = tid & 63;
    const int quad = lane >> 4, l15 = lane & 15;
    const int f = blockIdx.x;
    const int m0 = (f & 63) * 128, n0 = (f >> 6) * 128;
    const int wm = (wid >> 1) * 64, wn = (wid & 1) * 64;

    size_t aoff[2], boff[2];
    int dsto[2];
#pragma unroll
    for (int i = 0; i < 2; ++i) {
        int s = tid + i * 256;
        int row = s >> 2, c8 = (s & 3) << 3;
        aoff[i] = (size_t)(m0 + row) * K + c8;
        boff[i] = (size_t)(n0 + row) * K + c8;
        dsto[i] = s * 8;
    }

    f32x4 acc[4][4];
#pragma unroll
    for (int i = 0; i < 4; ++i)
#pragma unroll
        for (int j = 0; j < 4; ++j) acc[i][j] = f32x4{0.f, 0.f, 0.f, 0.f};

#pragma unroll
    for (int t = 0; t < 2; ++t) {
        const int bo = t * 8192, k0 = t * 32;
#pragma unroll
        for (int i = 0; i < 2; ++i) {
            gll16(A + aoff[i] + k0, SH + bo + dsto[i]);
            gll16(Wb + boff[i] + k0, SH + bo + 4096 + dsto[i]);
        }
    }

    for (int it = 0; it < 32; ++it) {
        const int cur = (it % 3) * 8192;
        if (it < 31) WAIT_BARRIER(4);
        else         WAIT_BARRIER(0);
        if (it + 2 < 32) {
            const int nxt = ((it + 2) % 3) * 8192;
            const int k0n = (it + 2) * 32;
#pragma unroll
            for (int i = 0; i < 2; ++i) {
                gll16(A + aoff[i] + k0n, SH + nxt + dsto[i]);
                gll16(Wb + boff[i] + k0n, SH + nxt + 4096 + dsto[i]);
            }
        }
        short8 av[4], bv[4];
#pragma unroll
        for (int i = 0; i < 4; ++i)
            av[i] = *(const short8*)(SH + cur + (wm + i * 16 + l15) * 32 + quad * 8);
#pragma unroll
        for (int j = 0; j < 4; ++j)
            bv[j] = *(const short8*)(SH + cur + 4096 + (wn + j * 16 + l15) * 32 + quad * 8);
#pragma unroll
        for (int i = 0; i < 4; ++i)
#pragma unroll
            for (int j = 0; j < 4; ++j)
                acc[i][j] = __builtin_amdgcn_mfma_f32_16x16x32_bf16(av[i], bv[j], acc[i][j], 0, 0, 0);
    }

#pragma unroll
    for (int j = 0; j < 4; ++j) {
        int col = n0 + wn + j * 16 + l15;
        float bb = bias[col];
#pragma unroll
        for (int i = 0; i < 4; ++i) {
            int row = m0 + wm + i * 16 + quad * 4;
#pragma unroll
            for (int r = 0; r < 4; ++r)
                Op[(size_t)(row + r) * 1024 + col] = acc[i][j][r] + bb;
        }
    }
}

// ---------------- flash attention: split-q waves, padded V LDS ---------------
// 1D grid 1024: bh = f&63 (XCD-sharing of K/V), qt = f>>6. Wave wid owns 32 q
// rows, processes the full 64-kv tile per iter. K: gll-staged, XOR-swizzled
// slots (bank-balanced b128 reads). V: REG-staged (depth-2, alternating static
// reg sets) + ds_write into a PADDED region (row stride 72 u16 = 144B): V b64
// read bank = (9*l15 + 2kt + 2quad) mod 32, 9 invertible mod 32 -> each
// quarter-wave covers 32 distinct banks -> kills the 64 conflict-cyc/wave-iter
// (8.4M/dispatch = 15%/CU) the 16B-slot-XOR layout caused on b64 half-reads.
// LDS: [buf 2][K 4096 u16 | V 64x72 u16] = 34 KB. Single drain barrier/iter.
__global__ __launch_bounds__(256, 3) void attn_kernel(
    const u16* __restrict__ qg, const u16* __restrict__ kg,
    const u16* __restrict__ vT, u16* __restrict__ xb)
{
    __shared__ __align__(16) u16 KV[2 * 8704];

    const int tid = threadIdx.x;
    const int wid = tid >> 6, lane = tid & 63;
    const int quad = lane >> 4, l15 = lane & 15;
    const int f = blockIdx.x;
    const int bh = f & 63, qt = f >> 6;
    const int b = bh >> 4, h = bh & 15;

    // ---- Q fragments (wave-owned 32 q-rows), loop-invariant, from global
    const u16* qbase = qg + ((size_t)(b * N_ + qt * 128 + wid * 32)) * C_ + h * 64;
    short8 qf[2][2];   // [qb][ch]: B-frag, col q = qb*16+l15, d = ch*32+quad*8+{0..7}
#pragma unroll
    for (int qb2 = 0; qb2 < 2; ++qb2)
#pragma unroll
        for (int ch = 0; ch < 2; ++ch)
            qf[qb2][ch] = *(const short8*)(qbase + (size_t)(qb2 * 16 + l15) * C_ + ch * 32 + quad * 8);

    // ---- K staging (gll, XOR pre-swizzled source; LDS dest lane-linear)
    const u16* kptr[2];
    int kdst[2];
#pragma unroll
    for (int i = 0; i < 2; ++i) {
        int s = tid + i * 256;
        int row = s >> 3, g = s & 7;
        int gsw = g ^ (row & 7);
        kptr[i] = kg + ((size_t)(b * M_ + row)) * C_ + h * 64 + gsw * 8;
        kdst[i] = s * 8;
    }

    // ---- V staging (reg-staged, linear source; padded ds_write dest)
    const u16* vsrc[2];
    int vdst[2];
#pragma unroll
    for (int i = 0; i < 2; ++i) {
        int idx = tid + i * 256;          // 512 chunks of 8 u16 = 64x64 tile
        int vrow = idx >> 3, c8 = idx & 7;
        vsrc[i] = vT + (((size_t)b * 16 + h) * 64 + vrow) * M_ + c8 * 8;
        vdst[i] = 4096 + vrow * 72 + c8 * 8;
    }

    f32x4 acc[4][2];  // [db][qb]: O^T[d=db*16+quad*4+reg][q=qb*16+l15]
#pragma unroll
    for (int i = 0; i < 4; ++i)
#pragma unroll
        for (int j = 0; j < 2; ++j) acc[i][j] = f32x4{0.f, 0.f, 0.f, 0.f};
    float lsum[2] = {0.f, 0.f};

    // K fragment XOR offsets (rows kt*16+l15 -> row&7 = l15&7)
    const int swr = l15 & 7;
    const int kxo0 = ((0 * 4 + quad) ^ swr) << 3;   // d 0..31
    const int kxo1 = ((1 * 4 + quad) ^ swr) << 3;   // d 32..63
    // V read offsets (padded, no swizzle): row db*16+l15, kv kt*16+quad*4
    int voff[4];
#pragma unroll
    for (int db = 0; db < 4; ++db)
        voff[db] = 4096 + (db * 16 + l15) * 72 + quad * 4;

    union { short4v s; uint32_t u[2]; } pfrag[2];

    short8 vstA[2], vstB[2];   // V reg sets: tile parity 0 -> A, 1 -> B

    // ---- prologue: K(0) gll -> buf0; V(0)->A, V(1)->B; ds_write V(0)
    gll16(kptr[0], KV + kdst[0]);
    gll16(kptr[1], KV + kdst[1]);
    vstA[0] = *(const short8*)(vsrc[0]);
    vstA[1] = *(const short8*)(vsrc[1]);
    vstB[0] = *(const short8*)(vsrc[0] + 64);
    vstB[1] = *(const short8*)(vsrc[1] + 64);
    *(short8*)(KV + vdst[0]) = vstA[0];   // compiler auto-waits the loads
    *(short8*)(KV + vdst[1]) = vstA[1];

#define ATTN_BODY(IT, VW, VL)                                                  \
    {                                                                          \
        const int cur = ((IT) & 1) * 8704;                                     \
        const int nxtb = (((IT) + 1) & 1) * 8704;                              \
        __syncthreads();                                                       \
        if ((IT) + 1 < 32) {                                                   \
            *(short8*)(KV + nxtb + vdst[0]) = VW[0];                           \
            *(short8*)(KV + nxtb + vdst[1]) = VW[1];                           \
            const size_t kvn = (size_t)((IT) + 1) * 64;                        \
            gll16(kptr[0] + kvn * C_, KV + nxtb + kdst[0]);                    \
            gll16(kptr[1] + kvn * C_, KV + nxtb + kdst[1]);                    \
        }                                                                      \
        if ((IT) + 2 < 32) {                                                   \
            VL[0] = *(const short8*)(vsrc[0] + ((IT) + 2) * 64);               \
            VL[1] = *(const short8*)(vsrc[1] + ((IT) + 2) * 64);               \
        }                                                                      \
        _Pragma("unroll")                                                      \
        for (int kt = 0; kt < 4; ++kt) {                                       \
            const int kbase = cur + (kt * 16 + l15) * 64;                      \
            short8 kf0 = *(const short8*)(KV + kbase + kxo0);                  \
            short8 kf1 = *(const short8*)(KV + kbase + kxo1);                  \
            f32x4 sc0 = f32x4{0.f, 0.f, 0.f, 0.f};                             \
            f32x4 sc1 = f32x4{0.f, 0.f, 0.f, 0.f};                             \
            sc0 = __builtin_amdgcn_mfma_f32_16x16x32_bf16(kf0, qf[0][0], sc0, 0, 0, 0); \
            sc1 = __builtin_amdgcn_mfma_f32_16x16x32_bf16(kf0, qf[1][0], sc1, 0, 0, 0); \
            sc0 = __builtin_amdgcn_mfma_f32_16x16x32_bf16(kf1, qf[0][1], sc0, 0, 0, 0); \
            sc1 = __builtin_amdgcn_mfma_f32_16x16x32_bf16(kf1, qf[1][1], sc1, 0, 0, 0); \
            _Pragma("unroll")                                                  \
            for (int qb2 = 0; qb2 < 2; ++qb2) {                                \
                const f32x4 sv = qb2 ? sc1 : sc0;                              \
                float e0 = EXP2F(sv[0]);                                       \
                float e1 = EXP2F(sv[1]);                                       \
                float e2 = EXP2F(sv[2]);                                       \
                float e3 = EXP2F(sv[3]);                                       \
                lsum[qb2] += (e0 + e1) + (e2 + e3);                            \
                pfrag[qb2].u[0] = __builtin_amdgcn_perm(__builtin_bit_cast(uint32_t, e1), \
                                                        __builtin_bit_cast(uint32_t, e0), 0x07060302u); \
                pfrag[qb2].u[1] = __builtin_amdgcn_perm(__builtin_bit_cast(uint32_t, e3), \
                                                        __builtin_bit_cast(uint32_t, e2), 0x07060302u); \
            }                                                                  \
            _Pragma("unroll")                                                  \
            for (int db = 0; db < 4; ++db) {                                   \
                short4v vv = *(const short4v*)(KV + cur + voff[db] + kt * 16); \
                acc[db][0] = mfma16x16x16_bf16(vv, pfrag[0].s, acc[db][0]);    \
                acc[db][1] = mfma16x16x16_bf16(vv, pfrag[1].s, acc[db][1]);    \
            }                                                                  \
        }                                                                      \
    }

    for (int it2 = 0; it2 < 16; ++it2) {
        ATTN_BODY(2 * it2,     vstB, vstA);   // write tile 2k+1 (set B), reload set A <- tile 2k+2
        ATTN_BODY(2 * it2 + 1, vstA, vstB);   // write tile 2k+2 (set A), reload set B <- tile 2k+3
    }
#undef ATTN_BODY

    // ---- epilogue: all wave-local. Denominator: sum lanes {l15, +16, +32, +48}
    lsum[0] += __shfl_xor(lsum[0], 16);
    lsum[0] += __shfl_xor(lsum[0], 32);
    lsum[1] += __shfl_xor(lsum[1], 16);
    lsum[1] += __shfl_xor(lsum[1], 32);
    const float dinv[2] = {1.f / lsum[0], 1.f / lsum[1]};

#pragma unroll
    for (int qb2 = 0; qb2 < 2; ++qb2) {
        size_t ob = ((size_t)(b * N_ + qt * 128 + wid * 32 + qb2 * 16 + l15)) * C_ + h * 64;
#pragma unroll
        for (int db = 0; db < 4; ++db) {
            ushort4 st;
            st.x = f2bf(acc[db][qb2][0] * dinv[qb2]);
            st.y = f2bf(acc[db][qb2][1] * dinv[qb2]);
            st.z = f2bf(acc[db][qb2][2] * dinv[qb2]);
            st.w = f2bf(acc[db][qb2][3] * dinv[qb2]);
            *(ushort4*)(xb + ob + db * 16 + quad * 4) = st;
        }
    }
}

extern "C" void kernel_launch(void* const* d_in, const int* in_sizes, int n_in,
                              void* d_out, int out_size, void* d_ws, size_t ws_size,
                              hipStream_t stream) {
    const float* query = (const float*)d_in[0];
    const float* key   = (const float*)d_in[1];
    const float* value = (const float*)d_in[2];
    const float* Wq    = (const float*)d_in[3];
    const float* Wk    = (const float*)d_in[4];
    const float* Wv    = (const float*)d_in[5];
    const float* Wpm   = (const float*)d_in[6];
    const float* bp    = (const float*)d_in[7];
    float* out = (float*)d_out;

    u16* base = (u16*)d_ws;
    u16* qf  = base;
    u16* kf  = base + (size_t)SC_;
    u16* vf  = base + (size_t)2 * SC_;
    u16* kb  = base + (size_t)3 * SC_;
    u16* Wqb = base + (size_t)4 * SC_;
    u16* Wkb = Wqb + CC_;
    u16* Wvb = Wkb + CC_;
    u16* Wpb = Wvb + CC_;
    u16* qb  = vf;   // alias (vf dead after v-GEMM... reused as Q-proj output)
    u16* xb  = qf;   // alias (qf dead after q-GEMM)
    u16* vTr = Wpb + CC_;   // vT in fresh workspace region (after weights)

    hipLaunchKernelGGL(convert_kernel, dim3(4096), dim3(256), 0, stream,
                       query, key, value, Wq, Wk, Wv, Wpm,
                       qf, kf, vf, Wqb, Wkb, Wvb, Wpb);

    hipLaunchKernelGGL(gemm_qkv, dim3(1536), dim3(256), 0, stream,
                       kf, Wkb, kb,
                       vf, Wvb, vTr,
                       qf, Wqb, qb,
                       0.125f * 1.44269504088896340736f);

    hipLaunchKernelGGL(attn_kernel, dim3(1024), dim3(256), 0, stream, qb, kb, vTr, xb);

    hipLaunchKernelGGL(gemm_p, dim3(512), dim3(256), 0, stream, xb, Wpb, bp, out);
}

// Round 8
// 325.274 us; speedup vs baseline: 1.0277x; 1.0277x over previous
//
#include <hip/hip_runtime.h>
#include <stdint.h>

#define B_ 4
#define N_ 2048
#define M_ 2048
#define C_ 1024
#define H_ 16
#define D_ 64
#define SC_ (B_*N_*C_)
#define CC_ (C_*C_)

typedef unsigned short u16;
typedef __attribute__((ext_vector_type(8))) short short8;
typedef __attribute__((ext_vector_type(4))) short short4v;
typedef __attribute__((ext_vector_type(4))) float f32x4;

#if __has_builtin(__builtin_amdgcn_exp2f)
#define EXP2F __builtin_amdgcn_exp2f
#else
#define EXP2F exp2f
#endif

__device__ inline u16 f2bf(float f) {
    union { float f; uint32_t u; } v; v.f = f;
    uint32_t r = v.u + 0x7fffu + ((v.u >> 16) & 1u);
    return (u16)(r >> 16);
}

// K=16 bf16 MFMA (v_mfma_f32_16x16x16_bf16): 2-reg operands, no zero padding.
__device__ inline f32x4 mfma16x16x16_bf16(short4v a, short4v b, f32x4 c) {
#if __has_builtin(__builtin_amdgcn_mfma_f32_16x16x16bf16_1k)
    return __builtin_amdgcn_mfma_f32_16x16x16bf16_1k(a, b, c, 0, 0, 0);
#else
    asm volatile("v_mfma_f32_16x16x16_bf16 %0, %1, %2, %0"
                 : "+v"(c) : "v"(a), "v"(b));
    return c;
#endif
}

__device__ inline void gll16(const u16* g, u16* l) {
    __builtin_amdgcn_global_load_lds(
        (const __attribute__((address_space(1))) void*)g,
        (__attribute__((address_space(3))) void*)l, 16, 0, 0);
}

// Counted-vmcnt barrier: retire all but the newest N VMEM ops, then block
// barrier. sched_barrier(0) keeps LDS reads from hoisting above (rule #18).
#define WAIT_BARRIER(N)                                         \
    do {                                                        \
        asm volatile("s_waitcnt vmcnt(" #N ")" ::: "memory");   \
        __builtin_amdgcn_s_barrier();                           \
        __builtin_amdgcn_sched_barrier(0);                      \
    } while (0)

// ---------------- pass 1: fp32 -> bf16 conversion of all GEMM inputs ----------
__global__ __launch_bounds__(256) void convert_kernel(
    const float* __restrict__ q, const float* __restrict__ k, const float* __restrict__ v,
    const float* __restrict__ wq, const float* __restrict__ wk,
    const float* __restrict__ wv, const float* __restrict__ wp,
    u16* __restrict__ qf, u16* __restrict__ kf, u16* __restrict__ vf,
    u16* __restrict__ wqb, u16* __restrict__ wkb, u16* __restrict__ wvb, u16* __restrict__ wpb)
{
    const int SC4 = SC_ / 4;
    const int CC4 = CC_ / 4;
    const int total = 3 * SC4 + 4 * CC4;
    for (int i = blockIdx.x * 256 + threadIdx.x; i < total; i += gridDim.x * 256) {
        const float* src; u16* dst; int off;
        if (i < 3 * SC4) {
            int seg = i >> 21;
            off = (i & (SC4 - 1)) << 2;
            src = seg == 0 ? q : seg == 1 ? k : v;
            dst = seg == 0 ? qf : seg == 1 ? kf : vf;
        } else {
            int j = i - 3 * SC4;
            int seg = j >> 18;
            off = (j & (CC4 - 1)) << 2;
            src = seg == 0 ? wq : seg == 1 ? wk : seg == 2 ? wv : wp;
            dst = seg == 0 ? wqb : seg == 1 ? wkb : seg == 2 ? wvb : wpb;
        }
        float4 val = *(const float4*)(src + off);
        ushort4 h;
        h.x = f2bf(val.x); h.y = f2bf(val.y); h.z = f2bf(val.z); h.w = f2bf(val.w);
        *(ushort4*)(dst + off) = h;
    }
}

// ---------------- merged Q/K/V projection GEMM, 1536 blocks -------------------
__global__ __launch_bounds__(256, 3) void gemm_qkv(
    const u16* __restrict__ A0, const u16* __restrict__ W0, u16* __restrict__ O0,
    const u16* __restrict__ A1, const u16* __restrict__ W1, u16* __restrict__ O1,
    const u16* __restrict__ A2, const u16* __restrict__ W2, u16* __restrict__ O2,
    float qscale)
{
    const int K = 1024;
    __shared__ u16 SH[3 * 8192];   // [buf 3][As 4096 u16 | Bs 4096 u16] = 48 KB
    const int tid = threadIdx.x;
    const int wid = tid >> 6, lane = tid & 63;
    const int quad = lane >> 4, l15 = lane & 15;
    const int gseg = blockIdx.x >> 9;
    const int f = blockIdx.x & 511;
    const u16* A  = gseg == 0 ? A0 : gseg == 1 ? A1 : A2;
    const u16* Wb = gseg == 0 ? W0 : gseg == 1 ? W1 : W2;
    u16* Op       = gseg == 0 ? O0 : gseg == 1 ? O1 : O2;
    const float scale = gseg == 2 ? qscale : 1.0f;

    const int m0 = (f & 63) * 128, n0 = (f >> 6) * 128;
    const int wm = (wid >> 1) * 64, wn = (wid & 1) * 64;

    size_t aoff[2], boff[2];
    int dsto[2];
#pragma unroll
    for (int i = 0; i < 2; ++i) {
        int s = tid + i * 256;
        int row = s >> 2, c8 = (s & 3) << 3;
        aoff[i] = (size_t)(m0 + row) * K + c8;
        boff[i] = (size_t)(n0 + row) * K + c8;
        dsto[i] = s * 8;
    }

    f32x4 acc[4][4];
#pragma unroll
    for (int i = 0; i < 4; ++i)
#pragma unroll
        for (int j = 0; j < 4; ++j) acc[i][j] = f32x4{0.f, 0.f, 0.f, 0.f};

#pragma unroll
    for (int t = 0; t < 2; ++t) {
        const int bo = t * 8192, k0 = t * 32;
#pragma unroll
        for (int i = 0; i < 2; ++i) {
            gll16(A + aoff[i] + k0, SH + bo + dsto[i]);
            gll16(Wb + boff[i] + k0, SH + bo + 4096 + dsto[i]);
        }
    }

    for (int it = 0; it < 32; ++it) {
        const int cur = (it % 3) * 8192;
        if (it < 31) WAIT_BARRIER(4);
        else         WAIT_BARRIER(0);
        if (it + 2 < 32) {
            const int nxt = ((it + 2) % 3) * 8192;
            const int k0n = (it + 2) * 32;
#pragma unroll
            for (int i = 0; i < 2; ++i) {
                gll16(A + aoff[i] + k0n, SH + nxt + dsto[i]);
                gll16(Wb + boff[i] + k0n, SH + nxt + 4096 + dsto[i]);
            }
        }
        short8 av[4], bv[4];
#pragma unroll
        for (int i = 0; i < 4; ++i)
            av[i] = *(const short8*)(SH + cur + (wm + i * 16 + l15) * 32 + quad * 8);
#pragma unroll
        for (int j = 0; j < 4; ++j)
            bv[j] = *(const short8*)(SH + cur + 4096 + (wn + j * 16 + l15) * 32 + quad * 8);
#pragma unroll
        for (int i = 0; i < 4; ++i)
#pragma unroll
            for (int j = 0; j < 4; ++j)
                acc[i][j] = __builtin_amdgcn_mfma_f32_16x16x32_bf16(av[i], bv[j], acc[i][j], 0, 0, 0);
    }

    if (gseg == 1) {   // V-proj: vT[((b*16+h)*64+d)][m'], kv columns permuted
                       // within each 64-tile: (kt,q4) bit-swap so attn's PV
                       // b128 slot-XOR reads are bank-conflict-free.
#pragma unroll
        for (int j = 0; j < 4; ++j) {
            int col = n0 + wn + j * 16 + l15;
            int hh = col >> 6, dd = col & 63;
#pragma unroll
            for (int i = 0; i < 4; ++i) {
                int row = m0 + wm + i * 16 + quad * 4;
                int bb = row >> 11, mm = row & 2047;
                int w = mm & 63;
                int mmp = (mm & ~63) | (((w >> 2) & 3) << 4) | (((w >> 4) & 3) << 2) | (w & 3);
                ushort4 hv;
                hv.x = f2bf(acc[i][j][0]);
                hv.y = f2bf(acc[i][j][1]);
                hv.z = f2bf(acc[i][j][2]);
                hv.w = f2bf(acc[i][j][3]);
                *(ushort4*)(Op + (((size_t)bb * 16 + hh) * 64 + dd) * 2048 + mmp) = hv;
            }
        }
    } else {           // K-proj / Q-proj: row-major bf16 (Q pre-scaled)
#pragma unroll
        for (int j = 0; j < 4; ++j) {
            int col = n0 + wn + j * 16 + l15;
#pragma unroll
            for (int i = 0; i < 4; ++i) {
                int row = m0 + wm + i * 16 + quad * 4;
#pragma unroll
                for (int r = 0; r < 4; ++r)
                    Op[(size_t)(row + r) * 1024 + col] = f2bf(acc[i][j][r] * scale);
            }
        }
    }
}

// ---------------- final projection GEMM (fp32 out + bias) ---------------------
__global__ __launch_bounds__(256) void gemm_p(
    const u16* __restrict__ A, const u16* __restrict__ Wb,
    const float* __restrict__ bias, float* __restrict__ Op)
{
    const int K = 1024;
    __shared__ u16 SH[3 * 8192];
    const int tid = threadIdx.x;
    const int wid = tid >> 6, lane = tid & 63;
    const int quad = lane >> 4, l15 = lane & 15;
    const int f = blockIdx.x;
    const int m0 = (f & 63) * 128, n0 = (f >> 6) * 128;
    const int wm = (wid >> 1) * 64, wn = (wid & 1) * 64;

    size_t aoff[2], boff[2];
    int dsto[2];
#pragma unroll
    for (int i = 0; i < 2; ++i) {
        int s = tid + i * 256;
        int row = s >> 2, c8 = (s & 3) << 3;
        aoff[i] = (size_t)(m0 + row) * K + c8;
        boff[i] = (size_t)(n0 + row) * K + c8;
        dsto[i] = s * 8;
    }

    f32x4 acc[4][4];
#pragma unroll
    for (int i = 0; i < 4; ++i)
#pragma unroll
        for (int j = 0; j < 4; ++j) acc[i][j] = f32x4{0.f, 0.f, 0.f, 0.f};

#pragma unroll
    for (int t = 0; t < 2; ++t) {
        const int bo = t * 8192, k0 = t * 32;
#pragma unroll
        for (int i = 0; i < 2; ++i) {
            gll16(A + aoff[i] + k0, SH + bo + dsto[i]);
            gll16(Wb + boff[i] + k0, SH + bo + 4096 + dsto[i]);
        }
    }

    for (int it = 0; it < 32; ++it) {
        const int cur = (it % 3) * 8192;
        if (it < 31) WAIT_BARRIER(4);
        else         WAIT_BARRIER(0);
        if (it + 2 < 32) {
            const int nxt = ((it + 2) % 3) * 8192;
            const int k0n = (it + 2) * 32;
#pragma unroll
            for (int i = 0; i < 2; ++i) {
                gll16(A + aoff[i] + k0n, SH + nxt + dsto[i]);
                gll16(Wb + boff[i] + k0n, SH + nxt + 4096 + dsto[i]);
            }
        }
        short8 av[4], bv[4];
#pragma unroll
        for (int i = 0; i < 4; ++i)
            av[i] = *(const short8*)(SH + cur + (wm + i * 16 + l15) * 32 + quad * 8);
#pragma unroll
        for (int j = 0; j < 4; ++j)
            bv[j] = *(const short8*)(SH + cur + 4096 + (wn + j * 16 + l15) * 32 + quad * 8);
#pragma unroll
        for (int i = 0; i < 4; ++i)
#pragma unroll
            for (int j = 0; j < 4; ++j)
                acc[i][j] = __builtin_amdgcn_mfma_f32_16x16x32_bf16(av[i], bv[j], acc[i][j], 0, 0, 0);
    }

#pragma unroll
    for (int j = 0; j < 4; ++j) {
        int col = n0 + wn + j * 16 + l15;
        float bb = bias[col];
#pragma unroll
        for (int i = 0; i < 4; ++i) {
            int row = m0 + wm + i * 16 + quad * 4;
#pragma unroll
            for (int r = 0; r < 4; ++r)
                Op[(size_t)(row + r) * 1024 + col] = acc[i][j][r] + bb;
        }
    }
}

// ---------------- flash attention: split-q waves, b128 V reads ---------------
// 1D grid 1024: bh = f&63 (XCD-sharing of K/V), qt = f>>6. Wave wid owns 32 q
// rows, processes the full 64-kv tile per iter. K and V both gll-staged with
// 16B slot-XOR pre-swizzle (R6 staging, measured conflict-free for b128).
// V columns are (kt,q4)-permuted by the producer GEMM so each lane's 4 kt
// fragments for its quad are 32B contiguous: V reads become 8 b128/wave-iter
// at slot (quad*2+p)^(l15&7) -- every consecutive-8-lane group covers all 8
// slots = all 32 banks. Kills the 16 b64x4-extra-cycle conflicts (8.39M/disp).
// O and denominator wave-local: epilogue = 2 shfl_xor + store. LDS 32 KB.
__global__ __launch_bounds__(256, 3) void attn_kernel(
    const u16* __restrict__ qg, const u16* __restrict__ kg,
    const u16* __restrict__ vT, u16* __restrict__ xb)
{
    __shared__ __align__(16) u16 KV[2 * 8192];   // [buf 2][Ks 4096 u16 | Vs 4096 u16]

    const int tid = threadIdx.x;
    const int wid = tid >> 6, lane = tid & 63;
    const int quad = lane >> 4, l15 = lane & 15;
    const int f = blockIdx.x;
    const int bh = f & 63, qt = f >> 6;
    const int b = bh >> 4, h = bh & 15;

    // ---- Q fragments (wave-owned 32 q-rows), loop-invariant, from global
    const u16* qbase = qg + ((size_t)(b * N_ + qt * 128 + wid * 32)) * C_ + h * 64;
    short8 qf[2][2];   // [qb][ch]: B-frag, col q = qb*16+l15, d = ch*32+quad*8+{0..7}
#pragma unroll
    for (int qb2 = 0; qb2 < 2; ++qb2)
#pragma unroll
        for (int ch = 0; ch < 2; ++ch)
            qf[qb2][ch] = *(const short8*)(qbase + (size_t)(qb2 * 16 + l15) * C_ + ch * 32 + quad * 8);

    // ---- staging pointers (XOR-swizzled global group; LDS dest lane-linear)
    const u16* kptr[2];
    const u16* vptr[2];
    int dsto[2];
#pragma unroll
    for (int i = 0; i < 2; ++i) {
        int s = tid + i * 256;
        int row = s >> 3, g = s & 7;
        int gsw = g ^ (row & 7);
        kptr[i] = kg + ((size_t)(b * M_ + row)) * C_ + h * 64 + gsw * 8;
        vptr[i] = vT + (((size_t)b * 16 + h) * 64 + row) * M_ + gsw * 8;
        dsto[i] = s * 8;
    }

    f32x4 acc[4][2];  // [db][qb]: O^T[d=db*16+quad*4+reg][q=qb*16+l15]
#pragma unroll
    for (int i = 0; i < 4; ++i)
#pragma unroll
        for (int j = 0; j < 2; ++j) acc[i][j] = f32x4{0.f, 0.f, 0.f, 0.f};
    float lsum[2] = {0.f, 0.f};

    // K fragment XOR offsets (rows kt*16+l15 -> row&7 = l15&7)
    const int swr = l15 & 7;
    const int kxo0 = ((0 * 4 + quad) ^ swr) << 3;   // d 0..31
    const int kxo1 = ((1 * 4 + quad) ^ swr) << 3;   // d 32..63
    // V read: row base per db; slot (quad*2+p)^swr holds kt=2p (low 8B) and
    // kt=2p+1 (high 8B) fragments for this lane's quad (column-permuted vT).
    int vpo[4];
#pragma unroll
    for (int db = 0; db < 4; ++db)
        vpo[db] = 4096 + (db * 16 + l15) * 64;
    const int vso[2] = { ((quad * 2 + 0) ^ swr) << 3, ((quad * 2 + 1) ^ swr) << 3 };

    union { short4v s; uint32_t u[2]; } pfrag[2];
    union V8 { short8 s8; short4v s4[2]; } vv[4];

    // prologue: tile 0 -> buf 0
#pragma unroll
    for (int i = 0; i < 2; ++i) {
        gll16(kptr[i], KV + dsto[i]);
        gll16(vptr[i], KV + 4096 + dsto[i]);
    }

    for (int it = 0; it < 32; ++it) {
        const int cur = (it & 1) * 8192;
        __syncthreads();   // drain == wait for tile `it`
        if (it + 1 < 32) {
            const int nxt = ((it + 1) & 1) * 8192;
            const int kvn = (it + 1) * 64;
#pragma unroll
            for (int i = 0; i < 2; ++i) {
                gll16(kptr[i] + (size_t)kvn * C_, KV + nxt + dsto[i]);
                gll16(vptr[i] + kvn, KV + nxt + 4096 + dsto[i]);
            }
        }

#pragma unroll
        for (int kt = 0; kt < 4; ++kt) {
            // ---- S^T[16 kv][32 q] = K*Q^T  (A-frag row kv = kt*16+l15)
            const int kbase = cur + (kt * 16 + l15) * 64;
            short8 kf0 = *(const short8*)(KV + kbase + kxo0);
            short8 kf1 = *(const short8*)(KV + kbase + kxo1);
            f32x4 sc0 = f32x4{0.f, 0.f, 0.f, 0.f};
            f32x4 sc1 = f32x4{0.f, 0.f, 0.f, 0.f};
            sc0 = __builtin_amdgcn_mfma_f32_16x16x32_bf16(kf0, qf[0][0], sc0, 0, 0, 0);
            sc1 = __builtin_amdgcn_mfma_f32_16x16x32_bf16(kf0, qf[1][0], sc1, 0, 0, 0);
            sc0 = __builtin_amdgcn_mfma_f32_16x16x32_bf16(kf1, qf[0][1], sc0, 0, 0, 0);
            sc1 = __builtin_amdgcn_mfma_f32_16x16x32_bf16(kf1, qf[1][1], sc1, 0, 0, 0);

            // ---- p = exp2(s), truncate-pack to bf16 (lane-local B-frag)
#pragma unroll
            for (int qb2 = 0; qb2 < 2; ++qb2) {
                const f32x4 sv = qb2 ? sc1 : sc0;
                float e0 = EXP2F(sv[0]);
                float e1 = EXP2F(sv[1]);
                float e2 = EXP2F(sv[2]);
                float e3 = EXP2F(sv[3]);
                lsum[qb2] += (e0 + e1) + (e2 + e3);
                pfrag[qb2].u[0] = __builtin_amdgcn_perm(__builtin_bit_cast(uint32_t, e1),
                                                        __builtin_bit_cast(uint32_t, e0), 0x07060302u);
                pfrag[qb2].u[1] = __builtin_amdgcn_perm(__builtin_bit_cast(uint32_t, e3),
                                                        __builtin_bit_cast(uint32_t, e2), 0x07060302u);
            }

            // ---- V fragment loads: one b128 per db per kt-PAIR (kt even)
            if ((kt & 1) == 0) {
                const int p = kt >> 1;
#pragma unroll
                for (int db = 0; db < 4; ++db)
                    vv[db].s8 = *(const short8*)(KV + cur + vpo[db] + vso[p]);
            }

            // ---- O^T += V^T * P^T  (K=16 MFMA; A-frag k = kt*16+quad*4+{0..3})
#pragma unroll
            for (int db = 0; db < 4; ++db) {
                acc[db][0] = mfma16x16x16_bf16(vv[db].s4[kt & 1], pfrag[0].s, acc[db][0]);
                acc[db][1] = mfma16x16x16_bf16(vv[db].s4[kt & 1], pfrag[1].s, acc[db][1]);
            }
        }
    }

    // ---- epilogue: all wave-local. Denominator: sum lanes {l15, +16, +32, +48}
    lsum[0] += __shfl_xor(lsum[0], 16);
    lsum[0] += __shfl_xor(lsum[0], 32);
    lsum[1] += __shfl_xor(lsum[1], 16);
    lsum[1] += __shfl_xor(lsum[1], 32);
    const float dinv[2] = {1.f / lsum[0], 1.f / lsum[1]};

#pragma unroll
    for (int qb2 = 0; qb2 < 2; ++qb2) {
        size_t ob = ((size_t)(b * N_ + qt * 128 + wid * 32 + qb2 * 16 + l15)) * C_ + h * 64;
#pragma unroll
        for (int db = 0; db < 4; ++db) {
            ushort4 st;
            st.x = f2bf(acc[db][qb2][0] * dinv[qb2]);
            st.y = f2bf(acc[db][qb2][1] * dinv[qb2]);
            st.z = f2bf(acc[db][qb2][2] * dinv[qb2]);
            st.w = f2bf(acc[db][qb2][3] * dinv[qb2]);
            *(ushort4*)(xb + ob + db * 16 + quad * 4) = st;
        }
    }
}

extern "C" void kernel_launch(void* const* d_in, const int* in_sizes, int n_in,
                              void* d_out, int out_size, void* d_ws, size_t ws_size,
                              hipStream_t stream) {
    const float* query = (const float*)d_in[0];
    const float* key   = (const float*)d_in[1];
    const float* value = (const float*)d_in[2];
    const float* Wq    = (const float*)d_in[3];
    const float* Wk    = (const float*)d_in[4];
    const float* Wv    = (const float*)d_in[5];
    const float* Wpm   = (const float*)d_in[6];
    const float* bp    = (const float*)d_in[7];
    float* out = (float*)d_out;

    u16* base = (u16*)d_ws;
    u16* qf  = base;
    u16* kf  = base + (size_t)SC_;
    u16* vf  = base + (size_t)2 * SC_;
    u16* kb  = base + (size_t)3 * SC_;
    u16* Wqb = base + (size_t)4 * SC_;
    u16* Wkb = Wqb + CC_;
    u16* Wvb = Wkb + CC_;
    u16* Wpb = Wvb + CC_;
    u16* qb  = vf;   // alias (vf dead after v-GEMM; reused as Q-proj output)
    u16* xb  = qf;   // alias (qf dead after q-GEMM)
    u16* vTr = Wpb + CC_;   // vT in fresh workspace region (after weights)

    hipLaunchKernelGGL(convert_kernel, dim3(4096), dim3(256), 0, stream,
                       query, key, value, Wq, Wk, Wv, Wpm,
                       qf, kf, vf, Wqb, Wkb, Wvb, Wpb);

    hipLaunchKernelGGL(gemm_qkv, dim3(1536), dim3(256), 0, stream,
                       kf, Wkb, kb,
                       vf, Wvb, vTr,
                       qf, Wqb, qb,
                       0.125f * 1.44269504088896340736f);

    hipLaunchKernelGGL(attn_kernel, dim3(1024), dim3(256), 0, stream, qb, kb, vTr, xb);

    hipLaunchKernelGGL(gemm_p, dim3(512), dim3(256), 0, stream, xb, Wpb, bp, out);
}